// Round 16
// baseline (393.309 us; speedup 1.0000x reference)
//
#include <hip/hip_runtime.h>
#include <cstdint>
#include <cstddef>

#define T_LEN 4096
#define C_DIM 256
#define B_DIM 8
#define K_TOP 4

typedef __attribute__((ext_vector_type(8))) short bf16x8;
typedef __attribute__((ext_vector_type(4))) float f32x4;

// tanh-form GELU: x * sigmoid(1.59577x + 0.0713548x^3); |delta| vs exact
// erf-GELU ~2.5e-4, below the bf16 quant noise already in the buffers.
__device__ __forceinline__ float gelu_fast(float x) {
    float x2 = x * x;
    float a = x * fmaf(0.071354816f, x2, 1.595769122f);
    float e = __expf(-a);
    return __fdividef(x, 1.0f + e);
}

__device__ __forceinline__ unsigned short f2bf(float f) {
    uint32_t u = __float_as_uint(f);
    uint32_t r = (u + 0x7fffu + ((u >> 16) & 1u)) >> 16;
    return (unsigned short)r;
}

__device__ __forceinline__ float bf2f(unsigned short v) {
    uint32_t u = ((uint32_t)v) << 16;
    return __uint_as_float(u);
}

typedef __attribute__((address_space(3))) uint32_t lds_u32_t;
typedef __attribute__((address_space(1))) const uint32_t gbl_u32_t;

__device__ __forceinline__ void lds_load16(const void* g, void* l) {
    __builtin_amdgcn_global_load_lds((gbl_u32_t*)g, (lds_u32_t*)l, 16, 0, 0);
}

// raw barriers with explicit (counted) waits
#define BAR_VM0()                                                      \
    do {                                                               \
        asm volatile("s_waitcnt vmcnt(0) lgkmcnt(0)" ::: "memory");    \
        __builtin_amdgcn_s_barrier();                                  \
        __builtin_amdgcn_sched_barrier(0);                             \
    } while (0)
#define BAR_VM2()                                                      \
    do {                                                               \
        asm volatile("s_waitcnt vmcnt(2) lgkmcnt(0)" ::: "memory");    \
        __builtin_amdgcn_s_barrier();                                  \
        __builtin_amdgcn_sched_barrier(0);                             \
    } while (0)
#define BAR_LGKM()                                                     \
    do {                                                               \
        asm volatile("s_waitcnt lgkmcnt(0)" ::: "memory");             \
        __builtin_amdgcn_s_barrier();                                  \
        __builtin_amdgcn_sched_barrier(0);                             \
    } while (0)

// padded LDS index for FFT: +1 float per 32
#define FPAD(i) ((i) + ((i) >> 5))

// ------------------------------------------------------------------
// Fallback (no-xT tier): xbf = bf16(x), plus zero page
// ------------------------------------------------------------------
__global__ __launch_bounds__(256) void cvt_x_kernel(const float4* __restrict__ x,
                                                    ushort4* __restrict__ xbf,
                                                    unsigned short* __restrict__ zbuf) {
    size_t i = (size_t)blockIdx.x * 256 + threadIdx.x;
    float4 v = x[i];
    ushort4 o;
    o.x = f2bf(v.x); o.y = f2bf(v.y); o.z = f2bf(v.z); o.w = f2bf(v.w);
    xbf[i] = o;
    if (blockIdx.x == 0 && threadIdx.x < 256) zbuf[threadIdx.x] = 0;
}

// ------------------------------------------------------------------
// Fused: one read of x produces xT[b][c][t] (BF16, for FFT) AND
// xbf[b][t][c] (bf16, for conv), plus the zero page.
// ------------------------------------------------------------------
__global__ __launch_bounds__(256) void transpose_cvtx_kernel(const float* __restrict__ x,
                                                             unsigned short* __restrict__ xTb,
                                                             unsigned short* __restrict__ xbf,
                                                             unsigned short* __restrict__ zbuf) {
    __shared__ float tile[32][33];
    const int b = blockIdx.z;
    const int t0 = blockIdx.x * 32, c0 = blockIdx.y * 32;
    const int lx = threadIdx.x & 31, ly = threadIdx.x >> 5;
    const float* xp = x + (size_t)b * T_LEN * C_DIM;
    unsigned short* xbp = xbf + (size_t)b * T_LEN * C_DIM;
    unsigned short* op = xTb + (size_t)b * C_DIM * T_LEN;
    for (int rr = ly; rr < 32; rr += 8) {
        float v = xp[(size_t)(t0 + rr) * C_DIM + c0 + lx];
        tile[rr][lx] = v;
        xbp[(size_t)(t0 + rr) * C_DIM + c0 + lx] = f2bf(v);
    }
    __syncthreads();
    for (int rr = ly; rr < 32; rr += 8)
        op[(size_t)(c0 + rr) * T_LEN + t0 + lx] = f2bf(tile[lx][rr]);
    if (blockIdx.x == 0 && blockIdx.y == 0 && blockIdx.z == 0)
        zbuf[threadIdx.x] = 0;
}

// ------------------------------------------------------------------
// fp32 src[K][N] -> bf16 MFMA fragment tiles (A- and B-compatible).
// Used for W1 (256x1024), W2 (1024x256), and Wc (2304x256 flat HWIO).
// ------------------------------------------------------------------
__global__ __launch_bounds__(256) void repack_frag_kernel(const float* __restrict__ src,
                                                          unsigned short* __restrict__ dst,
                                                          int K, int N) {
    int idx = blockIdx.x * 256 + threadIdx.x;  // (tile, lane)
    int total = (N >> 4) * (K >> 5) * 64;
    if (idx >= total) return;
    int lane = idx & 63, tile = idx >> 6;
    int ktiles = K >> 5;
    int tile_n = tile / ktiles, tile_k = tile % ktiles;
    int col = tile_n * 16 + (lane & 15);
    int k0 = tile_k * 32 + (lane >> 4) * 8;
    __align__(16) unsigned short v[8];
#pragma unroll
    for (int j = 0; j < 8; j++) v[j] = f2bf(src[(size_t)(k0 + j) * N + col]);
    *(uint4*)(dst + (size_t)idx * 8) = *(const uint4*)v;
}

// ------------------------------------------------------------------
// 2-for-1 real FFT: one complex 4096-pt FFT per CHANNEL PAIR
// (re = channel 2c, im = channel 2c+1, from bf16 xT), then Hermitian
// separation.  Fused radix-2 stage-pairs, pad-32 LDS.  bf16 mags out.
// ------------------------------------------------------------------
__global__ __launch_bounds__(256) void fft_mag_pair_kernel(const unsigned short* __restrict__ xTb,
                                                           unsigned short* __restrict__ mags) {
    const int bx = blockIdx.x;
    const int b = bx >> 7;
    const int c0 = (bx & 127) * 2;
    const int tid = threadIdx.x;

    __shared__ __align__(16) float re[4224];
    __shared__ __align__(16) float im[4224];
    __shared__ __align__(16) float twr[2048];
    __shared__ __align__(16) float twi[2048];

    for (int u = tid; u < 2048; u += 256) {
        float ang = -6.283185307179586f * (float)u / 4096.0f;
        float s, co;
        sincosf(ang, &s, &co);
        twr[u] = co;
        twi[u] = s;
    }

    {
        const uint4* r0 = (const uint4*)(xTb + ((size_t)(b * C_DIM + c0)) * T_LEN);
        const uint4* r1 = (const uint4*)(xTb + ((size_t)(b * C_DIM + c0 + 1)) * T_LEN);
        for (int e8 = tid; e8 < 512; e8 += 256) {
            uint4 v0 = r0[e8], v1 = r1[e8];
            const unsigned short* p0 = (const unsigned short*)&v0;
            const unsigned short* p1 = (const unsigned short*)&v1;
            int e = e8 * 8;
#pragma unroll
            for (int j = 0; j < 8; j++) {
                int r = (int)(__brev((unsigned)(e + j)) >> 20);
                re[FPAD(r)] = bf2f(p0[j]);
                im[FPAD(r)] = bf2f(p1[j]);
            }
        }
    }
    __syncthreads();

#pragma unroll
    for (int sp = 0; sp < 6; sp++) {
        const int h = 1 << (2 * sp);
        const int t1s = 11 - 2 * sp;
        const int t2s = 10 - 2 * sp;
        for (int j = tid; j < 1024; j += 256) {
            int p = j & (h - 1);
            int G = j >> (2 * sp);
            int base = G * 4 * h + p;
            int iA = FPAD(base), iB = FPAD(base + h);
            int iC = FPAD(base + 2 * h), iD = FPAD(base + 3 * h);
            float w1r = twr[p << t1s], w1i = twi[p << t1s];
            float w2r = twr[p << t2s], w2i = twi[p << t2s];
            float Ar = re[iA], Ai = im[iA], Br = re[iB], Bi = im[iB];
            float Cr = re[iC], Ci = im[iC], Dr = re[iD], Di = im[iD];
            float tBr = w1r * Br - w1i * Bi, tBi = w1r * Bi + w1i * Br;
            float tDr = w1r * Dr - w1i * Di, tDi = w1r * Di + w1i * Dr;
            float A1r = Ar + tBr, A1i = Ai + tBi;
            float B1r = Ar - tBr, B1i = Ai - tBi;
            float C1r = Cr + tDr, C1i = Ci + tDi;
            float D1r = Cr - tDr, D1i = Ci - tDi;
            float tCr = w2r * C1r - w2i * C1i, tCi = w2r * C1i + w2i * C1r;
            float uDr = w2r * D1r - w2i * D1i, uDi = w2r * D1i + w2i * D1r;
            float vDr = uDi, vDi = -uDr;
            re[iA] = A1r + tCr; im[iA] = A1i + tCi;
            re[iC] = A1r - tCr; im[iC] = A1i - tCi;
            re[iB] = B1r + vDr; im[iB] = B1i + vDi;
            re[iD] = B1r - vDr; im[iD] = B1i - vDi;
        }
        __syncthreads();
    }

    unsigned short* mp0 = mags + ((size_t)(b * C_DIM + c0)) * 2048;
    unsigned short* mp1 = mp0 + 2048;
    for (int u = tid; u < 2048; u += 256) {
        int f = u + 1;
        int g = 4096 - f;
        int jf = FPAD(f), jg = FPAD(g);
        float ar = re[jf], ai = im[jf];
        float br = re[jg], bi = im[jg];
        float xr = ar + br, xi = ai - bi;  // 2*X_c
        float yr = ai + bi, yi = br - ar;  // 2*X_{c+1}
        mp0[u] = f2bf(0.5f * sqrtf(xr * xr + xi * xi));
        mp1[u] = f2bf(0.5f * sqrtf(yr * yr + yi * yi));
    }
}

// ------------------------------------------------------------------
// Fallback per-channel FFT (strided fp32 x input), bf16 mags out.
// ------------------------------------------------------------------
__global__ __launch_bounds__(256) void fft_mag_kernel(const float* __restrict__ src,
                                                      unsigned short* __restrict__ mags) {
    const int bx = blockIdx.x;
    const int b = bx >> 8;
    const int c = bx & 255;
    const int tid = threadIdx.x;

    __shared__ __align__(16) float re[4224];
    __shared__ __align__(16) float im[4224];
    __shared__ __align__(16) float twr[2048];
    __shared__ __align__(16) float twi[2048];

    for (int u = tid; u < 2048; u += 256) {
        float ang = -6.283185307179586f * (float)u / 4096.0f;
        float s, co;
        sincosf(ang, &s, &co);
        twr[u] = co;
        twi[u] = s;
    }
    for (int i = tid; i < 4224; i += 256) im[i] = 0.0f;

    const float* xp = src + (size_t)b * T_LEN * C_DIM + c;
    for (int e = tid; e < 4096; e += 256) {
        int r = (int)(__brev((unsigned)e) >> 20);
        re[FPAD(r)] = xp[(size_t)e * C_DIM];
    }
    __syncthreads();

#pragma unroll
    for (int sp = 0; sp < 6; sp++) {
        const int h = 1 << (2 * sp);
        const int t1s = 11 - 2 * sp;
        const int t2s = 10 - 2 * sp;
        for (int j = tid; j < 1024; j += 256) {
            int p = j & (h - 1);
            int G = j >> (2 * sp);
            int base = G * 4 * h + p;
            int iA = FPAD(base), iB = FPAD(base + h);
            int iC = FPAD(base + 2 * h), iD = FPAD(base + 3 * h);
            float w1r = twr[p << t1s], w1i = twi[p << t1s];
            float w2r = twr[p << t2s], w2i = twi[p << t2s];
            float Ar = re[iA], Ai = im[iA], Br = re[iB], Bi = im[iB];
            float Cr = re[iC], Ci = im[iC], Dr = re[iD], Di = im[iD];
            float tBr = w1r * Br - w1i * Bi, tBi = w1r * Bi + w1i * Br;
            float tDr = w1r * Dr - w1i * Di, tDi = w1r * Di + w1i * Dr;
            float A1r = Ar + tBr, A1i = Ai + tBi;
            float B1r = Ar - tBr, B1i = Ai - tBi;
            float C1r = Cr + tDr, C1i = Ci + tDi;
            float D1r = Cr - tDr, D1i = Ci - tDi;
            float tCr = w2r * C1r - w2i * C1i, tCi = w2r * C1i + w2i * C1r;
            float uDr = w2r * D1r - w2i * D1i, uDi = w2r * D1i + w2i * D1r;
            float vDr = uDi, vDi = -uDr;
            re[iA] = A1r + tCr; im[iA] = A1i + tCi;
            re[iC] = A1r - tCr; im[iC] = A1i - tCi;
            re[iB] = B1r + vDr; im[iB] = B1i + vDi;
            re[iD] = B1r - vDr; im[iD] = B1i - vDi;
        }
        __syncthreads();
    }

    unsigned short* mp = mags + ((size_t)(b * C_DIM + c)) * 2048;
    for (int u = tid; u < 2048; u += 256) {
        int f = FPAD(u + 1);
        mp[u] = f2bf(sqrtf(re[f] * re[f] + im[f] * im[f]));
    }
}

// ------------------------------------------------------------------
// partial[b][cc][u] = sum over 32 channels of mags (bf16 in, fp32 out)
// ------------------------------------------------------------------
__global__ __launch_bounds__(256) void reduce_amps_kernel(const unsigned short* __restrict__ mags,
                                                          float* __restrict__ partial) {
    const int b = blockIdx.z, cc = blockIdx.y;
    const int u = blockIdx.x * 256 + threadIdx.x;
    const unsigned short* mp = mags + ((size_t)b * C_DIM + cc * 32) * 2048 + u;
    float s = 0.0f;
    for (int c = 0; c < 32; c++) s += bf2f(mp[(size_t)c * 2048]);
    partial[((size_t)b * 8 + cc) * 2048 + u] = s;
}

// ------------------------------------------------------------------
// Per-batch top-4 (value desc, ties -> lower index), periods, softmax
// ------------------------------------------------------------------
__global__ __launch_bounds__(256) void topk_kernel(const float* __restrict__ partial,
                                                   int* __restrict__ meta_p,
                                                   float* __restrict__ meta_w) {
    const int b = blockIdx.x;
    const int tid = threadIdx.x;
    __shared__ float v[2048];
    __shared__ float rv[256];
    __shared__ int ri[256];
    __shared__ float topv[K_TOP];
    __shared__ int topi[K_TOP];

    for (int u = tid; u < 2048; u += 256) {
        float s = 0.0f;
        for (int cc = 0; cc < 8; cc++) s += partial[((size_t)b * 8 + cc) * 2048 + u];
        v[u] = s * (1.0f / (float)C_DIM);
    }

    for (int k = 0; k < K_TOP; k++) {
        __syncthreads();
        float bv = -1e30f;
        int bi = 2048;
        for (int u = tid; u < 2048; u += 256) {
            float val = v[u];
            if (val > bv) { bv = val; bi = u; }
        }
        rv[tid] = bv;
        ri[tid] = bi;
        __syncthreads();
        for (int s = 128; s > 0; s >>= 1) {
            if (tid < s) {
                float ov = rv[tid + s];
                int oi = ri[tid + s];
                if (ov > rv[tid] || (ov == rv[tid] && oi < ri[tid])) {
                    rv[tid] = ov;
                    ri[tid] = oi;
                }
            }
            __syncthreads();
        }
        if (tid == 0) {
            topv[k] = rv[0];
            topi[k] = ri[0];
            v[ri[0]] = -1e30f;
        }
    }
    __syncthreads();
    if (tid == 0) {
        float mx = topv[0];
        for (int k = 1; k < K_TOP; k++) mx = fmaxf(mx, topv[k]);
        float e[K_TOP], se = 0.0f;
        for (int k = 0; k < K_TOP; k++) { e[k] = expf(topv[k] - mx); se += e[k]; }
        for (int k = 0; k < K_TOP; k++) {
            int idx = topi[k];
            int d = (idx >= 1) ? idx : 1;
            int p = T_LEN / d;
            if (p < 1) p = 1;
            meta_p[b * K_TOP + k] = p;
            meta_w[b * K_TOP + k] = e[k] / se;
        }
    }
}

// ------------------------------------------------------------------
// Conv as MFMA GEMM v5: operand-bandwidth split.
// B (weights) as fragment-tiled per-lane 16B GLOBAL loads (L1-resident
// 16KB K-slice shared by co-resident blocks) -- same repack+consume
// pair as the FF kernel's W1frag/W2frag.  LDS holds ONLY A: 256-row
// block tile (wave 128x64, acc[8][4]) at 3 x 16KB = 48KB -> still
// 2 blocks/CU, and half the ds_reads per FLOP of the 128-tile.
// Pipeline: stage A(s+2) while computing s; B loads issued first each
// iter so their data-dep wait (in-order vmcnt) forces A(s+1) complete
// before MFMA; barrier = vmcnt(2) (A(s+2) pair in flight) + lgkm(0).
// ------------------------------------------------------------------
__global__ __launch_bounds__(512) void conv_mfma_kernel(const unsigned short* __restrict__ xbf,
                                                        const unsigned short* __restrict__ WcFrag,
                                                        const float* __restrict__ bc,
                                                        const int* __restrict__ meta_p,
                                                        const unsigned short* __restrict__ zbuf,
                                                        unsigned short* __restrict__ convbufs,
                                                        size_t conv_stride, int koff) {
    const int b = blockIdx.y;
    const int kz = blockIdx.z;
    const int n = meta_p[b * K_TOP + koff + kz];
    const int row0 = blockIdx.x * 256;
    const int tid = threadIdx.x, w = tid >> 6, lane = tid & 63;
    const int wm = w >> 2, wn = w & 3;  // wave tile: rows [wm*128,+128), cols [wn*64,+64)

    __shared__ __align__(16) unsigned short Al[3][256 * 32];  // 3 x 16 KB

    const int ra = tid >> 2;
    const int swz = ((tid & 3) ^ ((ra >> 1) & 3)) * 8;
    int ti[2], tj[2];
#pragma unroll
    for (int s01 = 0; s01 < 2; s01++) {
        int t = row0 + ra + s01 * 128;
        ti[s01] = t / n;
        tj[s01] = t - ti[s01] * n;
    }
    const unsigned short* xb = xbf + (size_t)b * T_LEN * C_DIM;
    const unsigned short* baseA0;
    const unsigned short* baseA1;

    auto computeA = [&](int q, int s01) -> const unsigned short* {
        int di = q / 3 - 1, dj = q % 3 - 1;
        int ii = ti[s01] + di, jj = tj[s01] + dj;
        int tp = ii * n + jj;
        bool ok = (jj >= 0) && (jj < n) && (ii >= 0) && (tp < T_LEN);
        return ok ? (xb + (size_t)tp * C_DIM + swz) : (zbuf + swz);
    };

    // B-fragment base pointers: tile_n = wn*4+nn, ktiles = 72
    const unsigned short* Wb[4];
#pragma unroll
    for (int nn = 0; nn < 4; nn++)
        Wb[nn] = WcFrag + (((size_t)(wn * 4 + nn) * 72) * 64 + lane) * 8;

    f32x4 acc[8][4];
#pragma unroll
    for (int m = 0; m < 8; m++)
#pragma unroll
        for (int nn = 0; nn < 4; nn++) acc[m][nn] = (f32x4){0.f, 0.f, 0.f, 0.f};

    // prologue: stage K-steps 0 and 1 (q = 0 for both)
    baseA0 = computeA(0, 0);
    baseA1 = computeA(0, 1);
#pragma unroll
    for (int t = 0; t < 2; t++) {
        lds_load16(baseA0 + t * 32, &Al[t][tid * 8]);
        lds_load16(baseA1 + t * 32, &Al[t][(tid + 512) * 8]);
    }

    int cur = 0, stb = 2;
    for (int s = 0; s < 72; s++) {
        BAR_VM2();  // A(s) resident (A(s+1) forced by prev iter's B-wait;
                    // newest-2 allowance = this iter's A(s+2) stage pair)

        // ---- B fragments for step s (global, L1-resident; issued first) ----
        bf16x8 bfr[4];
#pragma unroll
        for (int nn = 0; nn < 4; nn++)
            bfr[nn] = *(const bf16x8*)(Wb[nn] + (size_t)s * 512);

        // ---- stage A(s+2) into buf stb ----
        const int t = s + 2;
        if (t < 72) {
            if ((t & 7) == 0) {
                int q = t >> 3;
                baseA0 = computeA(q, 0);
                baseA1 = computeA(q, 1);
            }
            const int ko = (t & 7) * 32;
            lds_load16(baseA0 + ko, &Al[stb][tid * 8]);
            lds_load16(baseA1 + ko, &Al[stb][(tid + 512) * 8]);
        }

        __builtin_amdgcn_s_setprio(1);
#pragma unroll
        for (int m = 0; m < 8; m++) {
            int row = wm * 128 + m * 16 + (lane & 15);
            bf16x8 af = *(const bf16x8*)((const char*)&Al[cur][0] + row * 64 +
                                         (((lane >> 4) * 16) ^ (((row >> 1) & 3) << 4)));
#pragma unroll
            for (int nn = 0; nn < 4; nn++)
                acc[m][nn] = __builtin_amdgcn_mfma_f32_16x16x32_bf16(af, bfr[nn], acc[m][nn], 0, 0, 0);
        }
        __builtin_amdgcn_s_setprio(0);

        cur = (cur == 2) ? 0 : cur + 1;
        stb = (stb == 2) ? 0 : stb + 1;
    }

    unsigned short* ob = convbufs + (size_t)kz * conv_stride + (size_t)b * T_LEN * C_DIM;
#pragma unroll
    for (int nn = 0; nn < 4; nn++) {
        int col = wn * 64 + nn * 16 + (lane & 15);
        float bs = bc[col];
#pragma unroll
        for (int m = 0; m < 8; m++) {
            int rbase = row0 + wm * 128 + m * 16 + (lane >> 4) * 4;
#pragma unroll
            for (int r = 0; r < 4; r++) {
                float v = acc[m][nn][r] + bs;
                ob[(size_t)(rbase + r) * C_DIM + col] = f2bf(gelu_fast(v));
            }
        }
    }
}

// ------------------------------------------------------------------
// Fused FF v5 (round-11, unchanged):
// out = osrc + (sum_k wk*gelu(A_k@W1+b1)) @ W2 + b2scale*b2
// ------------------------------------------------------------------
template <int KCNT>
__global__ __launch_bounds__(256, 2) void fused_ff_kernel(
    const unsigned short* __restrict__ convbufs, size_t conv_stride,
    const unsigned short* __restrict__ W1frag,
    const unsigned short* __restrict__ W2frag,
    const float* __restrict__ b1,
    const float* __restrict__ b2,
    const float* __restrict__ meta_w,
    float* __restrict__ out,
    const float* __restrict__ osrc,   // x (init) or out (accumulate)
    float b2scale, int koff) {
    const int tid = threadIdx.x;
    const int wn = tid >> 6, lane = tid & 63;
    const int row0 = blockIdx.x * 32;
    const int b = row0 >> 12;

    __shared__ __align__(16) unsigned short Asw[KCNT * 32 * 256];   // KCNT*16 KB
    __shared__ __align__(16) unsigned short Hsw[2][32 * 128];       // 2 x 8 KB

    float wkv[KCNT];
#pragma unroll
    for (int kc = 0; kc < KCNT; kc++) wkv[kc] = meta_w[b * K_TOP + koff + kc];

    // ---- stage all KCNT A-strips once (linear LDS dest, inv-swizzled src) ----
    {
        const unsigned short* base = convbufs + (size_t)row0 * C_DIM;
#pragma unroll
        for (int u = 0; u < KCNT * 4; u++) {
            int ch = u * 256 + tid;      // 16B chunk id
            int rfull = ch >> 5;         // row in Asw (= kc*32 + trow)
            int kc = rfull >> 5;
            int trow = rfull & 31;
            int cole = ((ch & 31) * 8) ^ ((rfull & 7) << 3);
            lds_load16(base + (size_t)kc * conv_stride + (size_t)trow * 256 + cole,
                       (unsigned short*)Asw + (size_t)ch * 8);
        }
    }

    f32x4 acc2[2][4];
#pragma unroll
    for (int t2 = 0; t2 < 2; t2++)
#pragma unroll
        for (int nn = 0; nn < 4; nn++) acc2[t2][nn] = (f32x4){0.f, 0.f, 0.f, 0.f};

    BAR_VM0();  // Asw landed

    for (int cc = 0; cc < 8; cc++) {
        const int par = cc & 1;

        // ---- GEMM1 (swapped) over all k: acc1[kc][n2][t2] = H^T frags ----
        f32x4 acc1[KCNT][2][2];
#pragma unroll
        for (int kc = 0; kc < KCNT; kc++)
#pragma unroll
            for (int n2 = 0; n2 < 2; n2++)
#pragma unroll
                for (int t2 = 0; t2 < 2; t2++) acc1[kc][n2][t2] = (f32x4){0.f, 0.f, 0.f, 0.f};

        __builtin_amdgcn_s_setprio(1);
#pragma unroll
        for (int ks = 0; ks < 8; ks++) {
            bf16x8 w1f[2];
#pragma unroll
            for (int n2 = 0; n2 < 2; n2++) {
                int tile_n = cc * 8 + wn * 2 + n2;
                w1f[n2] = *(const bf16x8*)(W1frag + ((size_t)(tile_n * 8 + ks) * 64 + lane) * 8);
            }
            bf16x8 af[KCNT][2];
#pragma unroll
            for (int kc = 0; kc < KCNT; kc++)
#pragma unroll
                for (int t2 = 0; t2 < 2; t2++) {
                    int row = kc * 32 + t2 * 16 + (lane & 15);
                    af[kc][t2] = *(const bf16x8*)((const char*)Asw + row * 512 +
                                                  ((ks * 64 + (lane >> 4) * 16) ^ ((row & 7) << 4)));
                }
#pragma unroll
            for (int kc = 0; kc < KCNT; kc++)
#pragma unroll
                for (int n2 = 0; n2 < 2; n2++)
#pragma unroll
                    for (int t2 = 0; t2 < 2; t2++)
                        acc1[kc][n2][t2] = __builtin_amdgcn_mfma_f32_16x16x32_bf16(
                            w1f[n2], af[kc][t2], acc1[kc][n2][t2], 0, 0, 0);
        }
        __builtin_amdgcn_s_setprio(0);

        // ---- combine: Hsw[par][t][h] = sum_k wk*gelu(acc1 + b1) (bf16) ----
#pragma unroll
        for (int n2 = 0; n2 < 2; n2++) {
            const int hloc = wn * 32 + n2 * 16 + (lane >> 4) * 4;  // 4 consecutive h
            f32x4 bb = *(const f32x4*)(b1 + cc * 128 + hloc);
#pragma unroll
            for (int t2 = 0; t2 < 2; t2++) {
                float hc[4];
#pragma unroll
                for (int r = 0; r < 4; r++) {
                    float s = 0.0f;
#pragma unroll
                    for (int kc = 0; kc < KCNT; kc++)
                        s += wkv[kc] * gelu_fast(acc1[kc][n2][t2][r] + bb[r]);
                    hc[r] = s;
                }
                uint32_t lo, hi;
                asm("v_cvt_pk_bf16_f32 %0, %1, %2" : "=v"(lo) : "v"(hc[0]), "v"(hc[1]));
                asm("v_cvt_pk_bf16_f32 %0, %1, %2" : "=v"(hi) : "v"(hc[2]), "v"(hc[3]));
                uint2 pk;
                pk.x = lo;
                pk.y = hi;
                int t = t2 * 16 + (lane & 15);
                *(uint2*)((char*)&Hsw[par][0] + t * 256 +
                          ((hloc * 2) ^ ((t & 7) << 4))) = pk;
            }
        }
        BAR_LGKM();  // Hsw[par] visible; global prefetches stay in flight

        // ---- GEMM2 once per chunk: acc2 += Hcomb @ W2chunk ----
        __builtin_amdgcn_s_setprio(1);
#pragma unroll
        for (int ks2 = 0; ks2 < 4; ks2++) {
            bf16x8 af2[2], w2f[4];
#pragma unroll
            for (int t2 = 0; t2 < 2; t2++) {
                int row = t2 * 16 + (lane & 15);
                af2[t2] = *(const bf16x8*)((const char*)&Hsw[par][0] + row * 256 +
                                           ((ks2 * 64 + (lane >> 4) * 16) ^ ((row & 7) << 4)));
            }
#pragma unroll
            for (int nn = 0; nn < 4; nn++) {
                int tile_n = wn * 4 + nn;
                int tile_k = cc * 4 + ks2;
                w2f[nn] = *(const bf16x8*)(W2frag + ((size_t)(tile_n * 32 + tile_k) * 64 + lane) * 8);
            }
#pragma unroll
            for (int t2 = 0; t2 < 2; t2++)
#pragma unroll
                for (int nn = 0; nn < 4; nn++)
                    acc2[t2][nn] = __builtin_amdgcn_mfma_f32_16x16x32_bf16(af2[t2], w2f[nn],
                                                                           acc2[t2][nn], 0, 0, 0);
        }
        __builtin_amdgcn_s_setprio(0);
        // no barrier: next chunk writes Hsw[par^1], whose readers (GEMM2 at
        // cc-1) are ordered before the BAR_LGKM above.
    }

    // ---- epilogue: out = osrc + acc2 + b2scale*b2 ----
#pragma unroll
    for (int nn = 0; nn < 4; nn++) {
        int col = wn * 64 + nn * 16 + (lane & 15);
        float bb = b2scale * b2[col];
#pragma unroll
        for (int t2 = 0; t2 < 2; t2++) {
            int rbase = row0 + t2 * 16 + (lane >> 4) * 4;
#pragma unroll
            for (int r = 0; r < 4; r++) {
                size_t idx = (size_t)(rbase + r) * C_DIM + col;
                out[idx] = osrc[idx] + acc2[t2][nn][r] + bb;
            }
        }
    }
}

// ------------------------------------------------------------------
extern "C" void kernel_launch(void* const* d_in, const int* in_sizes, int n_in,
                              void* d_out, int out_size, void* d_ws, size_t ws_size,
                              hipStream_t stream) {
    const float* x  = (const float*)d_in[0];
    const float* Wc = (const float*)d_in[1];
    const float* bc = (const float*)d_in[2];
    const float* W1 = (const float*)d_in[3];
    const float* b1 = (const float*)d_in[4];
    const float* W2 = (const float*)d_in[5];
    const float* b2 = (const float*)d_in[6];
    float* out = (float*)d_out;

    const size_t CONV_ELEMS = (size_t)B_DIM * T_LEN * C_DIM;     // 8M
    const size_t CONV_BYTES = CONV_ELEMS * 2;                    // 16.78 MB
    const size_t MAGS_BYTES = (size_t)B_DIM * C_DIM * 2048 * 2;  // 8.39 MB (bf16)
    const size_t XT_BYTES = (size_t)B_DIM * T_LEN * C_DIM * 2;   // 16.78 MB (bf16)

    // ---- fixed carve ----
    uint8_t* ws = (uint8_t*)d_ws;
    size_t off = 0;
    auto alloc = [&](size_t bytes) {
        size_t o = off;
        off = (off + bytes + 255) & ~(size_t)255;
        return o;
    };
    float* partial = (float*)(ws + alloc((size_t)B_DIM * 8 * 2048 * 4));
    int* meta_p = (int*)(ws + alloc(B_DIM * K_TOP * 4));
    float* meta_w = (float*)(ws + alloc(B_DIM * K_TOP * 4));
    unsigned short* xbf = (unsigned short*)(ws + alloc((size_t)B_DIM * T_LEN * C_DIM * 2));
    unsigned short* WcFrag = (unsigned short*)(ws + alloc((size_t)2304 * 256 * 2));
    unsigned short* W1frag = (unsigned short*)(ws + alloc((size_t)256 * 1024 * 2));
    unsigned short* W2frag = (unsigned short*)(ws + alloc((size_t)1024 * 256 * 2));
    unsigned short* zbuf = (unsigned short*)(ws + alloc(512));

    // ---- tiered regionA ----
    size_t remaining = (ws_size > off) ? (ws_size - off) : 0;
    uint8_t* regionA = ws + off;
    int tier;  // 2=FULL(4 convbufs), 1=MID(1 convbuf + xT), 0=MIN
    if (remaining >= 4 * CONV_BYTES) tier = 2;
    else if (remaining >= MAGS_BYTES + XT_BYTES) tier = 1;
    else tier = 0;

    unsigned short* mags = (unsigned short*)regionA;  // FFT phase (dead before conv)
    unsigned short* xTb = (unsigned short*)(regionA + ((tier == 2) ? CONV_BYTES : MAGS_BYTES));
    unsigned short* convbufs = (unsigned short*)regionA;
    const int use_xT = (tier >= 1);

    // 1. x -> {xTb, xbf, zbuf} in one read (fused); fallback: xbf only
    if (use_xT) {
        transpose_cvtx_kernel<<<dim3(T_LEN / 32, C_DIM / 32, B_DIM), 256, 0, stream>>>(
            x, xTb, xbf, zbuf);
    } else {
        cvt_x_kernel<<<dim3((B_DIM * T_LEN * C_DIM / 4) / 256), 256, 0, stream>>>(
            (const float4*)x, (ushort4*)xbf, zbuf);
    }

    // 2. weight prep: all three weights -> fragment tiles
    repack_frag_kernel<<<dim3(288), 256, 0, stream>>>(Wc, WcFrag, 2304, 256);
    repack_frag_kernel<<<dim3(128), 256, 0, stream>>>(W1, W1frag, 256, 1024);
    repack_frag_kernel<<<dim3(128), 256, 0, stream>>>(W2, W2frag, 1024, 256);

    // 3. FFT magnitudes (2-for-1 paired when xT available), reduce, top-4
    if (use_xT) {
        fft_mag_pair_kernel<<<dim3(B_DIM * 128), 256, 0, stream>>>(xTb, mags);
    } else {
        fft_mag_kernel<<<dim3(B_DIM * C_DIM), 256, 0, stream>>>(x, mags);
    }
    reduce_amps_kernel<<<dim3(2048 / 256, 8, B_DIM), 256, 0, stream>>>(mags, partial);
    topk_kernel<<<dim3(B_DIM), 256, 0, stream>>>(partial, meta_p, meta_w);

    // 4. conv (all k) then fused FF (combined over k)
    if (tier == 2) {
        conv_mfma_kernel<<<dim3(16, B_DIM, K_TOP), 512, 0, stream>>>(
            xbf, WcFrag, bc, meta_p, zbuf, convbufs, CONV_ELEMS, 0);
        fused_ff_kernel<4><<<dim3(B_DIM * T_LEN / 32), 256, 0, stream>>>(
            convbufs, CONV_ELEMS, W1frag, W2frag, b1, b2, meta_w, out, x, 1.0f, 0);
    } else {
        for (int k = 0; k < K_TOP; k++) {
            conv_mfma_kernel<<<dim3(16, B_DIM, 1), 512, 0, stream>>>(
                xbf, WcFrag, bc, meta_p, zbuf, convbufs, 0, k);
            fused_ff_kernel<1><<<dim3(B_DIM * T_LEN / 32), 256, 0, stream>>>(
                convbufs, 0, W1frag, W2frag, b1, b2, meta_w, out,
                (k == 0) ? x : out, (k == K_TOP - 1) ? 1.0f : 0.0f, k);
        }
    }
}